// Round 11
// baseline (360.104 us; speedup 1.0000x reference)
//
#include <hip/hip_runtime.h>
#include <cmath>
#include <type_traits>

#pragma clang fp contract(off)

#define NSAVE 101
#define NSUB  20
#define NCTRL 10
#define IV_PER_K 10   // 100 save intervals / 10 control intervals

typedef float v2f __attribute__((ext_vector_type(2)));

// Packed f32 fma via llvm.fma.v2f32 -> v_pk_fma_f32 (per-element IEEE,
// R8-verified bit-stable). Off-critical-chain work only; chain tails scalar
// so the short (B) parity never waits on the long (A/sqrt) parity.
__device__ __forceinline__ v2f pk_fma(v2f a, v2f b, v2f c) {
    return __builtin_elementwise_fma(a, b, c);
}

// np-faithful pow for the exponents that occur (generic fallback path only).
__device__ __forceinline__ float pow_np_f32(float x, float p) {
    if (p == 2.5f) return (x * x) * sqrtf(x);
    if (p == 1.0f) return x;
    if (p == 2.0f) return x * x;
    return powf(x, p);
}

// h-premultiplied Butcher constants (double product, rounded once)
#define HCF(x) ((float)(0.05 * (x)))
__device__ constexpr float HA21 = HCF(0.161);
__device__ constexpr float HA31 = HCF(-0.008480655492356989), HA32 = HCF(0.335480655492357);
__device__ constexpr float HA41 = HCF(2.8971530571054935),  HA42 = HCF(-6.359448489975075),  HA43 = HCF(4.3622954328695815);
__device__ constexpr float HA51 = HCF(5.325864828439257),   HA52 = HCF(-11.748883564062828), HA53 = HCF(7.4955393428898365), HA54 = HCF(-0.09249506636175525);
__device__ constexpr float HA61 = HCF(5.86145544294642),    HA62 = HCF(-12.92096931784711),  HA63 = HCF(8.159367898576159),  HA64 = HCF(-0.071584973281401), HA65 = HCF(-0.028269050394068383);
__device__ constexpr float HB1 = HCF(0.09646076681806523), HB2 = HCF(0.01), HB3 = HCF(0.4798896504144996);
__device__ constexpr float HB4 = HCF(1.379008574103742),   HB5 = HCF(-3.290069515436081), HB6 = HCF(2.324710524099774);

// p-coordinate additive constants: K_i = h * c_i (Butcher row sums), KY = h*sum(B)
__device__ constexpr float K2 = HCF(0.161);
__device__ constexpr float K3 = HCF(0.327);
__device__ constexpr float K4 = HCF(0.9);
__device__ constexpr float K5 = HCF(0.9800255409045097);
__device__ constexpr float K6 = (float)(0.05 * (5.86145544294642 - 12.92096931784711 + 8.159367898576159 - 0.071584973281401 - 0.028269050394068383));
__device__ constexpr float KY = (float)(0.05 * (0.09646076681806523 + 0.01 + 0.4798896504144996 + 1.379008574103742 - 3.290069515436081 + 2.324710524099774));

__global__ __launch_bounds__(256, 1) void toggle_tsit5_kernel(
    const float* __restrict__ init,
    const float* __restrict__ useq,
    const float* __restrict__ params,
    float* __restrict__ out,
    int B)
{
    const int tid = blockIdx.x * blockDim.x + threadIdx.x;

    // times = linspace(0,100,101): exact small integers in f32
    if (tid < NSAVE) out[(size_t)B * 222 + tid] = (float)tid;
    if (tid >= B) return;

    const float iptg_max = params[0];
    const float K        = params[1];
    const float n_iptg   = params[2];
    const float a1       = params[3];
    const float a2       = params[4];
    const float n_ab     = params[5];
    const float n_ba     = params[6];

    const int p = tid;
    const float* ub = useq + (size_t)p * (NCTRL * 2);

    // u clip+copy: 20 floats per trajectory, 16B aligned
    {
        float* dst = out + (size_t)B * 202 + (size_t)p * (NCTRL * 2);
        #pragma unroll
        for (int i = 0; i < 5; ++i) {
            float4 v = reinterpret_cast<const float4*>(ub)[i];
            v.x = fminf(fmaxf(v.x, 0.0f), 1.0f);
            v.y = fminf(fmaxf(v.y, 0.0f), 1.0f);
            v.z = fminf(fmaxf(v.z, 0.0f), 1.0f);
            v.w = fminf(fmaxf(v.w, 0.0f), 1.0f);
            reinterpret_cast<float4*>(dst)[i] = v;
        }
    }

    const bool special = (n_iptg == 2.0f) && (n_ab == 2.5f) && (n_ba == 1.0f);

    float* ys = out + (size_t)p * 202;
    int bad = 0;

    if (special) {
        // ---- parity-decoupled, A-side in p-coords (px = 1+zx): the expB add
        //      moves off the critical cycle; rB = rcp(px) directly. The y/B
        //      half's arithmetic is bit-identical to R10 (bases add +0.0f).
        //      Pre-tail fma pairs packed (inputs ready a stage early). ----
        float xA0 = init[(size_t)p * 2 + 0];
        float xB0 = init[(size_t)p * 2 + 1];
        {
            float wA = xA0, wB = xB0;
            if (!__builtin_isfinite(wA)) { wA = 0.0f; ++bad; }
            if (!__builtin_isfinite(wB)) { wB = 0.0f; ++bad; }
            *reinterpret_cast<float2*>(&ys[0]) = make_float2(wA, wB);
        }

        auto mk_den = [&](int k, int c) -> float {
            float u  = fminf(fmaxf(ub[k * 2 + c], 0.0f), 1.0f);
            float xx = (u * iptg_max) / K;
            return 1.0f + xx * xx;
        };

        float denA = mk_den(0, 0), denB = mk_den(0, 1);
        float rdA = 1.0f / denA,  rdB = 1.0f / denB;
        v2f s = { 1.0f + xA0 * rdA, xB0 * rdB };   // {px, zy}

        // compile-time packed broadcasts
        const v2f nHA21v = {-HA21, -HA21};
        const v2f nHA31v = {-HA31, -HA31}, nHA32v = {-HA32, -HA32};
        const v2f nHA41v = {-HA41, -HA41}, nHA42v = {-HA42, -HA42}, nHA43v = {-HA43, -HA43};
        const v2f nHA51v = {-HA51, -HA51}, nHA52v = {-HA52, -HA52}, nHA53v = {-HA53, -HA53}, nHA54v = {-HA54, -HA54};
        const v2f nHA61v = {-HA61, -HA61}, nHA62v = {-HA62, -HA62}, nHA63v = {-HA63, -HA63}, nHA64v = {-HA64, -HA64}, nHA65v = {-HA65, -HA65};
        const v2f nHB1v = {-HB1, -HB1}, nHB2v = {-HB2, -HB2}, nHB3v = {-HB3, -HB3}, nHB4v = {-HB4, -HB4}, nHB5v = {-HB5, -HB5}, nHB6v = {-HB6, -HB6};
        const v2f Kv2 = {K2, 0.0f}, Kv3 = {K3, 0.0f}, Kv4 = {K4, 0.0f},
                  Kv5 = {K5, 0.0f}, Kv6 = {K6, 0.0f}, KvY = {KY, 0.0f};

        // per-group runtime constants
        v2f nRN;
        float ANA21, ANB21, ANA32, ANB32, ANA43, ANB43, ANA54, ANB54, ANA65, ANB65, BNA6, BNB6;
        auto rebuild = [&](float rna, float rnb) {
            nRN = (v2f){-rna, -rnb};
            ANA21 = HA21 * rna; ANB21 = HA21 * rnb;
            ANA32 = HA32 * rna; ANB32 = HA32 * rnb;
            ANA43 = HA43 * rna; ANB43 = HA43 * rnb;
            ANA54 = HA54 * rna; ANB54 = HA54 * rnb;
            ANA65 = HA65 * rna; ANB65 = HA65 * rnb;
            BNA6  = HB6  * rna; BNB6  = HB6  * rnb;
        };
        rebuild(a1 * rdA, a2 * rdB);

        // exports: rA = rcp(1 + zy^2.5) (long chain), rB = rcp(px) (short)
        auto expA = [](float zyv) -> float {
            float q = __builtin_fmaf(zyv * zyv, __builtin_amdgcn_sqrtf(zyv), 1.0f);
            return __builtin_amdgcn_rcpf(q);
        };
        auto expB = [](float pxv) -> float {
            return __builtin_amdgcn_rcpf(pxv);
        };

        auto substep = [&](auto s6tag, v2f s6mul, v2f s6add) {
            const v2f s1 = s;
            float rA1 = expA(s1.y);
            float rB1 = expB(s1.x);
            v2f kh1 = pk_fma(nRN, (v2f){rA1, rB1}, s1);

            // stage 2
            v2f b2 = pk_fma(nHA21v, s1, s1 + Kv2);
            float zy2 = __builtin_fmaf(ANB21, rB1, b2.y);
            float rA2 = expA(zy2);
            float px2 = __builtin_fmaf(ANA21, rA1, b2.x);
            float rB2 = expB(px2);
            v2f s2 = {px2, zy2};
            v2f kh2 = pk_fma(nRN, (v2f){rA2, rB2}, s2);

            // stage 3
            v2f c3 = pk_fma(nHA31v, kh1, s1 + Kv3);
            v2f b3 = pk_fma(nHA32v, s2, c3);
            float zy3 = __builtin_fmaf(ANB32, rB2, b3.y);
            float rA3 = expA(zy3);
            float px3 = __builtin_fmaf(ANA32, rA2, b3.x);
            float rB3 = expB(px3);
            v2f s3 = {px3, zy3};
            v2f kh3 = pk_fma(nRN, (v2f){rA3, rB3}, s3);

            // stage 4
            v2f c4 = pk_fma(nHA42v, kh2, pk_fma(nHA41v, kh1, s1 + Kv4));
            v2f b4 = pk_fma(nHA43v, s3, c4);
            float zy4 = __builtin_fmaf(ANB43, rB3, b4.y);
            float rA4 = expA(zy4);
            float px4 = __builtin_fmaf(ANA43, rA3, b4.x);
            float rB4 = expB(px4);
            v2f s4 = {px4, zy4};
            v2f kh4 = pk_fma(nRN, (v2f){rA4, rB4}, s4);

            // stage 5
            v2f c5 = pk_fma(nHA53v, kh3, pk_fma(nHA52v, kh2, pk_fma(nHA51v, kh1, s1 + Kv5)));
            v2f b5 = pk_fma(nHA54v, s4, c5);
            float zy5 = __builtin_fmaf(ANB54, rB4, b5.y);
            float rA5 = expA(zy5);
            float px5 = __builtin_fmaf(ANA54, rA4, b5.x);
            float rB5 = expB(px5);
            v2f s5 = {px5, zy5};
            v2f kh5 = pk_fma(nRN, (v2f){rA5, rB5}, s5);

            // stage 6
            v2f c6 = pk_fma(nHA64v, kh4, pk_fma(nHA63v, kh3, pk_fma(nHA62v, kh2, pk_fma(nHA61v, kh1, s1 + Kv6))));
            v2f b6 = pk_fma(nHA65v, s5, c6);
            float zy6 = __builtin_fmaf(ANB65, rB5, b6.y);
            float px6 = __builtin_fmaf(ANA65, rA5, b6.x);
            v2f s6v = {px6, zy6};

            v2f w6 = s6v;
            if constexpr (decltype(s6tag)::value) w6 = pk_fma(s6mul, s6v, s6add);
            float rA6 = expA(w6.y);
            float rB6 = expB(w6.x);

            // y-update row
            v2f cy = pk_fma(nHB5v, kh5,
                     pk_fma(nHB4v, kh4,
                     pk_fma(nHB3v, kh3,
                     pk_fma(nHB2v, kh2,
                     pk_fma(nHB1v, kh1, s1 + KvY)))));
            v2f by = pk_fma(nHB6v, s6v, cy);
            float zyn = __builtin_fmaf(BNB6, rB6, by.y);
            float pxn = __builtin_fmaf(BNA6, rA6, by.x);
            s = (v2f){pxn, zyn};
        };

        #pragma unroll 1
        for (int k = 0; k < NCTRL; ++k) {
            const int kn = (k < NCTRL - 1) ? (k + 1) : k;
            const float denA_nx = mk_den(kn, 0), denB_nx = mk_den(kn, 1);
            const float rdA_nx = 1.0f / denA_nx, rdB_nx = 1.0f / denB_nx;
            const float ratioA = (kn != k) ? (denA * rdA_nx) : 1.0f;
            const float ratioB = (kn != k) ? (denB * rdB_nx) : 1.0f;
            const float cA = 1.0f - ratioA;    // px' = ratioA*px + (1-ratioA)
            const float bnd = 10.0f * (float)(k + 1);

            // data-independent boundary-crossing flag (exact f32 t replica)
            bool cross_k;
            {
                float tt = (float)(k * 10 + 9);
                #pragma unroll 1
                for (int j = 0; j < NSUB - 1; ++j) tt = tt + 0.05f;
                cross_k = (tt + 0.05f >= bnd);
            }

            #pragma unroll 1
            for (int iv2 = 0; iv2 < IV_PER_K; ++iv2) {
                const int iv = k * IV_PER_K + iv2;

                #pragma unroll 1
                for (int j = 0; j < NSUB - 1; ++j) {
                    substep(std::integral_constant<bool, false>{},
                            (v2f){1.0f, 1.0f}, (v2f){0.0f, 0.0f});
                }
                // peeled substep 19: stage-6 may cross the control boundary
                {
                    bool cross = (iv2 == IV_PER_K - 1) && cross_k;
                    v2f s6mul = cross ? (v2f){ratioA, ratioB} : (v2f){1.0f, 1.0f};
                    v2f s6add = cross ? (v2f){cA, 0.0f} : (v2f){0.0f, 0.0f};
                    substep(std::integral_constant<bool, true>{}, s6mul, s6add);
                }

                // unscale: xA = (px-1)*denA via fma; xB = zy*denB
                float wA = __builtin_fmaf(s.x, denA, -denA);
                float wB = s.y * denB;
                if (!__builtin_isfinite(wA)) { wA = 0.0f; ++bad; }
                if (!__builtin_isfinite(wB)) { wB = 0.0f; ++bad; }
                *reinterpret_cast<float2*>(&ys[(size_t)(iv + 1) * 2]) = make_float2(wA, wB);
            }

            // enter next group's coordinates
            s = pk_fma((v2f){ratioA, ratioB}, s, (v2f){cA, 0.0f});
            denA = denA_nx; rdA = rdA_nx;
            denB = denB_nx; rdB = rdB_nx;
            rebuild(a1 * rdA, a2 * rdB);
        }

    } else {
        // ---- generic fallback: straightforward, IEEE ----
        float A  = init[(size_t)p * 2 + 0];
        float Bc = init[(size_t)p * 2 + 1];
        {
            float wA = A, wB = Bc;
            if (!__builtin_isfinite(wA)) { wA = 0.0f; ++bad; }
            if (!__builtin_isfinite(wB)) { wB = 0.0f; ++bad; }
            ys[0] = wA; ys[1] = wB;
        }

        const float h = 0.05f;
        const float A21f = 0.161f;
        const float A31f = -0.008480655492356989f, A32f = 0.335480655492357f;
        const float A41f = 2.8971530571054935f,  A42f = -6.359448489975075f,  A43f = 4.3622954328695815f;
        const float A51f = 5.325864828439257f,   A52f = -11.748883564062828f, A53f = 7.4955393428898365f, A54f = -0.09249506636175525f;
        const float A61f = 5.86145544294642f,    A62f = -12.92096931784711f,  A63f = 8.159367898576159f,  A64f = -0.071584973281401f, A65f = -0.028269050394068383f;
        const float B1f = 0.09646076681806523f, B2f = 0.01f, B3f = 0.4798896504144996f;
        const float B4f = 1.379008574103742f,   B5f = -3.290069515436081f, B6f = 2.324710524099774f;

        auto mk_den = [&](int k, float& dA_, float& dB_) {
            float u0 = fminf(fmaxf(ub[k * 2 + 0], 0.0f), 1.0f);
            float u1 = fminf(fmaxf(ub[k * 2 + 1], 0.0f), 1.0f);
            float xA = (u0 * iptg_max) / K;
            float xB = (u1 * iptg_max) / K;
            dA_ = 1.0f + pow_np_f32(xA, n_iptg);
            dB_ = 1.0f + pow_np_f32(xB, n_iptg);
        };
        auto vf = [&](float rdA_, float rdB_, float As, float Bs, float& dA, float& dB) {
            float A_eff = As * rdA_;
            float B_eff = Bs * rdB_;
            float pB = pow_np_f32(B_eff, n_ab);
            float pA = pow_np_f32(A_eff, n_ba);
            dA = a1 / (1.0f + pB) - As;
            dB = a2 / (1.0f + pA) - Bs;
        };

        float denA, denB;
        mk_den(0, denA, denB);
        float rdenA = 1.0f / denA, rdenB = 1.0f / denB;

        #pragma unroll 1
        for (int k = 0; k < NCTRL; ++k) {
            int kn = (k < NCTRL - 1) ? (k + 1) : k;
            float denA_nx, denB_nx;
            mk_den(kn, denA_nx, denB_nx);
            float rdenA_nx = 1.0f / denA_nx, rdenB_nx = 1.0f / denB_nx;
            const float bnd = 10.0f * (float)(k + 1);

            #pragma unroll 1
            for (int iv2 = 0; iv2 < IV_PER_K; ++iv2) {
                const int iv = k * IV_PER_K + iv2;
                float t = (float)iv;
                #pragma unroll 1
                for (int j = 0; j < NSUB; ++j) {
                    bool nx = (iv2 == IV_PER_K - 1) && (j == NSUB - 1) && (t + 0.05f >= bnd);
                    float rdA6 = nx ? rdenA_nx : rdenA;
                    float rdB6 = nx ? rdenB_nx : rdenB;

                    float k1A, k1B, k2A, k2B, k3A, k3B, k4A, k4B, k5A, k5B, k6A, k6B;
                    vf(rdenA, rdenB, A, Bc, k1A, k1B);
                    vf(rdenA, rdenB, A + h * (A21f * k1A), Bc + h * (A21f * k1B), k2A, k2B);
                    vf(rdenA, rdenB, A + h * (A31f * k1A + A32f * k2A), Bc + h * (A31f * k1B + A32f * k2B), k3A, k3B);
                    vf(rdenA, rdenB, A + h * (A41f * k1A + A42f * k2A + A43f * k3A),
                                      Bc + h * (A41f * k1B + A42f * k2B + A43f * k3B), k4A, k4B);
                    vf(rdenA, rdenB, A + h * (A51f * k1A + A52f * k2A + A53f * k3A + A54f * k4A),
                                      Bc + h * (A51f * k1B + A52f * k2B + A53f * k3B + A54f * k4B), k5A, k5B);
                    vf(rdA6, rdB6,   A + h * (A61f * k1A + A62f * k2A + A63f * k3A + A64f * k4A + A65f * k5A),
                                      Bc + h * (A61f * k1B + A62f * k2B + A63f * k3B + A64f * k4B + A65f * k5B), k6A, k6B);

                    A  = A  + h * (B1f * k1A + B2f * k2A + B3f * k3A + B4f * k4A + B5f * k5A + B6f * k6A);
                    Bc = Bc + h * (B1f * k1B + B2f * k2B + B3f * k3B + B4f * k4B + B5f * k5B + B6f * k6B);
                    t  = t + h;
                }
                float wA = A, wB = Bc;
                if (!__builtin_isfinite(wA)) { wA = 0.0f; ++bad; }
                if (!__builtin_isfinite(wB)) { wB = 0.0f; ++bad; }
                ys[(size_t)(iv + 1) * 2 + 0] = wA;
                ys[(size_t)(iv + 1) * 2 + 1] = wB;
            }
            denA = denA_nx; denB = denB_nx;
            rdenA = rdenA_nx; rdenB = rdenB_nx;
        }
    }

    if (bad) atomicAdd(out + (size_t)B * 222 + NSAVE, (float)bad);
}

extern "C" void kernel_launch(void* const* d_in, const int* in_sizes, int n_in,
                              void* d_out, int out_size, void* d_ws, size_t ws_size,
                              hipStream_t stream) {
    const float* init   = (const float*)d_in[0];
    const float* useq   = (const float*)d_in[1];
    const float* params = (const float*)d_in[2];
    float* out = (float*)d_out;

    const int B = in_sizes[0] / 2;

    // zero the n_bad accumulator slot (graph-capture-safe async memset)
    hipMemsetAsync(out + (size_t)B * 222 + NSAVE, 0, sizeof(float), stream);

    const int block = 256;
    const int grid  = (B + block - 1) / block;
    hipLaunchKernelGGL(toggle_tsit5_kernel, dim3(grid), dim3(block), 0, stream,
                       init, useq, params, out, B);
}